// Round 1
// baseline (125.088 us; speedup 1.0000x reference)
//
#include <hip/hip_runtime.h>
#include <math.h>

#define NF 32
#define NB 1100
#define NE 8
#define NH 4
#define NBATCH 1024
#define NFH 128  // NF*NH

__device__ __forceinline__ float fexp2(float x){
#if __has_builtin(__builtin_amdgcn_exp2f)
  return __builtin_amdgcn_exp2f(x);
#else
  return exp2f(x);
#endif
}

// bins[i] exactly as np.linspace(-1, 300, 1100) in float64:
// step = 301/1099 (f64), bins[i] = fl(fl(i*step) + (-1)), bins[1099] = 300.0 forced.
__device__ __forceinline__ double bin_at(int i){
  #pragma clang fp contract(off)
  const double step = 301.0 / 1099.0;
  if (i == NB - 1) return 300.0;
  return (double)i * step + (-1.0);
}

// ---------------- K1: bin search + embedding gather + QKV projection ----------------
__global__ __launch_bounds__(256) void k1_embed_qkv(
    const float* __restrict__ x, const float* __restrict__ emb,
    const float* __restrict__ W, const float* __restrict__ bias,
    float* __restrict__ q_ws, float* __restrict__ kv_ws)
{
  __shared__ float sW[192];
  __shared__ float sB[24];
  const int tid = threadIdx.x;
  if (tid < 192) sW[tid] = W[tid];
  if (tid < 24)  sB[tid] = bias[tid];
  __syncthreads();

  const int f = blockIdx.y;
  const int b = blockIdx.x * 256 + tid;

  float xv = x[b * NF + f];
  xv = fminf(fmaxf(xv, -1.0f), 300.0f);
  const double xd = (double)xv;

  // searchsorted side='left': first i with bins[i] >= xd
  int lo = 0, hi = NB;
  while (lo < hi) {
    const int mid = (lo + hi) >> 1;
    if (bin_at(mid) < xd) lo = mid + 1; else hi = mid;
  }
  const int idx = lo;  // in [0, 1099] since xd <= 300 = bins[1099]

  const float4* ep = (const float4*)(emb + ((size_t)f * NB + idx) * NE);
  const float4 e0 = ep[0], e1 = ep[1];
  const float xe[8] = {e0.x, e0.y, e0.z, e0.w, e1.x, e1.y, e1.z, e1.w};

  float qv[8], kv[8], vv[8];
  #pragma unroll
  for (int i = 0; i < 8; ++i) { qv[i] = sB[i]; kv[i] = sB[8+i]; vv[i] = sB[16+i]; }
  #pragma unroll
  for (int j = 0; j < 8; ++j) {
    const float xj = xe[j];
    #pragma unroll
    for (int i = 0; i < 8; ++i) {
      qv[i] = fmaf(xj, sW[      i*8 + j], qv[i]);
      kv[i] = fmaf(xj, sW[ 64 + i*8 + j], kv[i]);
      vv[i] = fmaf(xj, sW[128 + i*8 + j], vv[i]);
    }
  }

  // q pre-scaled by log2(e)/sqrt(hd) so K2 can use exp2 directly
  const float QS = (float)(1.4426950408889634 / 1.4142135623730951);
  float2* qp = (float2*)q_ws;
  float4* kvp = (float4*)kv_ws;
  #pragma unroll
  for (int h = 0; h < NH; ++h) {
    const int fh = f * NH + h;
    qp [fh * NBATCH + b] = make_float2(qv[2*h] * QS, qv[2*h+1] * QS);
    kvp[fh * NBATCH + b] = make_float4(kv[2*h], kv[2*h+1], vv[2*h], vv[2*h+1]);
  }
}

// ---------------- K2: batch-attention per (f,h), single-pass softmax ----------------
__global__ __launch_bounds__(256) void k2_attn(
    const float* __restrict__ q_ws, const float* __restrict__ kv_ws,
    float* __restrict__ o_ws)
{
  __shared__ float4 skv[NBATCH];   // k0,k1,v0,v1 per batch row: 16 KB
  __shared__ float sred[4];
  const int tid = threadIdx.x;
  const int fh = blockIdx.y;

  // stage K/V and find max ||k||^2 (for the Cauchy-Schwarz softmax bound)
  const float4* kvg = (const float4*)kv_ws + (size_t)fh * NBATCH;
  float mx2 = 0.0f;
  #pragma unroll
  for (int i = 0; i < 4; ++i) {
    const float4 t = kvg[i * 256 + tid];
    skv[i * 256 + tid] = t;
    mx2 = fmaxf(mx2, fmaf(t.x, t.x, t.y * t.y));
  }
  #pragma unroll
  for (int off = 32; off >= 1; off >>= 1)
    mx2 = fmaxf(mx2, __shfl_xor(mx2, off, 64));
  if ((tid & 63) == 0) sred[tid >> 6] = mx2;
  __syncthreads();
  const float Mn = sqrtf(fmaxf(fmaxf(sred[0], sred[1]), fmaxf(sred[2], sred[3])));

  const int b = blockIdx.x * 256 + tid;   // one query row per thread
  const float2 q = ((const float2*)q_ws)[(size_t)fh * NBATCH + b];
  const float m = sqrtf(fmaf(q.x, q.x, q.y * q.y)) * Mn;  // >= all scaled scores

  float l = 0.0f, o0 = 0.0f, o1 = 0.0f;
  #pragma unroll 4
  for (int c = 0; c < NBATCH; ++c) {
    const float4 kv = skv[c];                               // LDS broadcast
    const float s = fmaf(q.x, kv.x, fmaf(q.y, kv.y, -m));   // scaled score - m <= 0
    const float p = fexp2(s);
    l += p;
    o0 = fmaf(p, kv.z, o0);
    o1 = fmaf(p, kv.w, o1);
  }
  const float inv = 1.0f / l;
  ((float2*)o_ws)[(size_t)fh * NBATCH + b] = make_float2(o0 * inv, o1 * inv);
}

// ---------------- K_comb: fold out_proj into the final linear ----------------
// Wcomb[t][f*8+e'] = sum_i lin_w[t][f*8+i] * out_proj_w[i][e']
// bcomb[t] = lin_b[t] + sum_{f,i} lin_w[t][f*8+i] * out_proj_b[i]
__global__ void k_comb(const float* __restrict__ opw, const float* __restrict__ opb,
                       const float* __restrict__ lw,  const float* __restrict__ lb,
                       float* __restrict__ Wcomb, float* __restrict__ bcomb)
{
  __shared__ float sWo[64];
  const int tid = threadIdx.x;
  if (tid < 64) sWo[tid] = opw[tid];
  __syncthreads();
  for (int i = tid; i < 4096; i += 256) {
    const int t = i >> 8, fe = i & 255;
    const int f8 = fe & ~7, e2 = fe & 7;
    float acc = 0.0f;
    #pragma unroll
    for (int e = 0; e < 8; ++e) acc = fmaf(lw[t*256 + f8 + e], sWo[e*8 + e2], acc);
    Wcomb[i] = acc;
  }
  if (tid < 16) {
    float acc = lb[tid];
    for (int fe = 0; fe < 256; ++fe) acc = fmaf(lw[tid*256 + fe], opb[fe & 7], acc);
    bcomb[tid] = acc;
  }
}

// ---------------- K3: logits = o . Wcomb^T + bcomb, softmax over 16 ----------------
__global__ __launch_bounds__(256) void k3_final(
    const float* __restrict__ o_ws, const float* __restrict__ Wcomb,
    const float* __restrict__ bcomb, float* __restrict__ out)
{
  const int gid = blockIdx.x * 256 + threadIdx.x;  // 16384 threads
  const int b = gid >> 4;
  const int t = gid & 15;
  const float2* op = (const float2*)o_ws;
  const float2* wp = (const float2*)Wcomb + t * 128;
  float acc = bcomb[t];
  #pragma unroll 8
  for (int fh = 0; fh < NFH; ++fh) {
    const float2 ov = op[(size_t)fh * NBATCH + b];
    const float2 wv = wp[fh];
    acc = fmaf(ov.x, wv.x, fmaf(ov.y, wv.y, acc));
  }
  // softmax across the 16 lanes sharing b (lanes are 16-aligned groups in a wave)
  float mx = acc;
  #pragma unroll
  for (int off = 8; off >= 1; off >>= 1) mx = fmaxf(mx, __shfl_xor(mx, off, 64));
  const float p = expf(acc - mx);
  float s = p;
  #pragma unroll
  for (int off = 8; off >= 1; off >>= 1) s += __shfl_xor(s, off, 64);
  out[gid] = p / s;
}

extern "C" void kernel_launch(void* const* d_in, const int* in_sizes, int n_in,
                              void* d_out, int out_size, void* d_ws, size_t ws_size,
                              hipStream_t stream)
{
  const float* x   = (const float*)d_in[0];
  const float* emb = (const float*)d_in[1];
  const float* ipw = (const float*)d_in[2];
  const float* ipb = (const float*)d_in[3];
  const float* opw = (const float*)d_in[4];
  const float* opb = (const float*)d_in[5];
  const float* lw  = (const float*)d_in[6];
  const float* lb  = (const float*)d_in[7];

  float* ws    = (float*)d_ws;
  float* q_ws  = ws;             // 128*1024*2 = 262144 floats
  float* kv_ws = ws + 262144;    // 128*1024*4 = 524288 floats
  float* o_ws  = ws + 786432;    // 128*1024*2 = 262144 floats
  float* Wcomb = ws + 1048576;   // 4096 floats
  float* bcomb = ws + 1052672;   // 16 floats  (total ~4.02 MB)

  k1_embed_qkv<<<dim3(4, NF), 256, 0, stream>>>(x, emb, ipw, ipb, q_ws, kv_ws);
  k_comb<<<1, 256, 0, stream>>>(opw, opb, lw, lb, Wcomb, bcomb);
  k2_attn<<<dim3(4, NFH), 256, 0, stream>>>(q_ws, kv_ws, o_ws);
  k3_final<<<64, 256, 0, stream>>>(o_ws, Wcomb, bcomb, (float*)d_out);
}

// Round 2
// 109.707 us; speedup vs baseline: 1.1402x; 1.1402x over previous
//
#include <hip/hip_runtime.h>
#include <math.h>

#define NF 32
#define NB 1100
#define NE 8
#define NH 4
#define NBATCH 1024
#define NFH 128  // NF*NH

__device__ __forceinline__ float fexp2(float x){
#if __has_builtin(__builtin_amdgcn_exp2f)
  return __builtin_amdgcn_exp2f(x);
#else
  return exp2f(x);
#endif
}

// bins[i] exactly as np.linspace(-1, 300, 1100) in float64:
// step = 301/1099 (f64), bins[i] = fl(fl(i*step) + (-1)), bins[1099] = 300.0 forced.
__device__ __forceinline__ double bin_at(int i){
  #pragma clang fp contract(off)
  const double step = 301.0 / 1099.0;
  if (i == NB - 1) return 300.0;
  return (double)i * step + (-1.0);
}

// ---------------- K1: bin search + embedding gather + QKV projection ----------------
__global__ __launch_bounds__(256) void k1_embed_qkv(
    const float* __restrict__ x, const float* __restrict__ emb,
    const float* __restrict__ W, const float* __restrict__ bias,
    float* __restrict__ q_ws, float* __restrict__ kv_ws)
{
  __shared__ float sW[192];
  __shared__ float sB[24];
  const int tid = threadIdx.x;
  if (tid < 192) sW[tid] = W[tid];
  if (tid < 24)  sB[tid] = bias[tid];
  __syncthreads();

  const int f = blockIdx.y;
  const int b = blockIdx.x * 256 + tid;

  float xv = x[b * NF + f];
  xv = fminf(fmaxf(xv, -1.0f), 300.0f);
  const double xd = (double)xv;

  // searchsorted side='left': first i with bins[i] >= xd
  int lo = 0, hi = NB;
  while (lo < hi) {
    const int mid = (lo + hi) >> 1;
    if (bin_at(mid) < xd) lo = mid + 1; else hi = mid;
  }
  const int idx = lo;  // in [0, 1099] since xd <= 300 = bins[1099]

  const float4* ep = (const float4*)(emb + ((size_t)f * NB + idx) * NE);
  const float4 e0 = ep[0], e1 = ep[1];
  const float xe[8] = {e0.x, e0.y, e0.z, e0.w, e1.x, e1.y, e1.z, e1.w};

  float qv[8], kv[8], vv[8];
  #pragma unroll
  for (int i = 0; i < 8; ++i) { qv[i] = sB[i]; kv[i] = sB[8+i]; vv[i] = sB[16+i]; }
  #pragma unroll
  for (int j = 0; j < 8; ++j) {
    const float xj = xe[j];
    #pragma unroll
    for (int i = 0; i < 8; ++i) {
      qv[i] = fmaf(xj, sW[      i*8 + j], qv[i]);
      kv[i] = fmaf(xj, sW[ 64 + i*8 + j], kv[i]);
      vv[i] = fmaf(xj, sW[128 + i*8 + j], vv[i]);
    }
  }

  // q pre-scaled by log2(e)/sqrt(hd) so K2 can use exp2 directly
  const float QS = (float)(1.4426950408889634 / 1.4142135623730951);
  float2* qp = (float2*)q_ws;
  float4* kvp = (float4*)kv_ws;
  #pragma unroll
  for (int h = 0; h < NH; ++h) {
    const int fh = f * NH + h;
    qp [fh * NBATCH + b] = make_float2(qv[2*h] * QS, qv[2*h+1] * QS);
    kvp[fh * NBATCH + b] = make_float4(kv[2*h], kv[2*h+1], vv[2*h], vv[2*h+1]);
  }
}

// ---------------- K2: batch-attention per (f,h), single-pass softmax ----------------
// 512 threads: 256 q-rows x 2 c-halves (512 c each), pairwise LDS merge.
__global__ __launch_bounds__(512) void k2_attn(
    const float* __restrict__ q_ws, const float* __restrict__ kv_ws,
    float* __restrict__ o_ws)
{
  __shared__ float4 skv[NBATCH];   // k0,k1,v0,v1 per batch row: 16 KB
  __shared__ float sred[8];
  __shared__ float sl[256], so0[256], so1[256];
  const int tid = threadIdx.x;     // 0..511
  const int fh = blockIdx.y;

  // stage K/V and find max ||k||^2 (for the Cauchy-Schwarz softmax bound)
  const float4* kvg = (const float4*)kv_ws + (size_t)fh * NBATCH;
  const float4 t0 = kvg[tid], t1 = kvg[tid + 512];
  skv[tid] = t0;
  skv[tid + 512] = t1;
  float mx2 = fmaxf(fmaf(t0.x, t0.x, t0.y * t0.y), fmaf(t1.x, t1.x, t1.y * t1.y));
  #pragma unroll
  for (int off = 32; off >= 1; off >>= 1)
    mx2 = fmaxf(mx2, __shfl_xor(mx2, off, 64));
  if ((tid & 63) == 0) sred[tid >> 6] = mx2;
  __syncthreads();
  float Mn2 = sred[0];
  #pragma unroll
  for (int w = 1; w < 8; ++w) Mn2 = fmaxf(Mn2, sred[w]);
  const float Mn = sqrtf(Mn2);

  const int qi = tid & 255;
  const int half = tid >> 8;
  const int b = blockIdx.x * 256 + qi;   // one query row per thread pair
  const float2 q = ((const float2*)q_ws)[(size_t)fh * NBATCH + b];
  const float negm = -sqrtf(fmaf(q.x, q.x, q.y * q.y)) * Mn;  // -(bound >= all scores)

  float l = 0.0f, o0 = 0.0f, o1 = 0.0f;
  const int c0 = half << 9;
  #pragma unroll 8
  for (int c = 0; c < 512; ++c) {
    const float4 kv = skv[c0 + c];                            // LDS broadcast
    const float s = fmaf(q.x, kv.x, fmaf(q.y, kv.y, negm));   // scaled score - m <= 0
    const float p = fexp2(s);
    l += p;
    o0 = fmaf(p, kv.z, o0);
    o1 = fmaf(p, kv.w, o1);
  }
  if (half == 1) { sl[qi] = l; so0[qi] = o0; so1[qi] = o1; }
  __syncthreads();
  if (half == 0) {
    l += sl[qi]; o0 += so0[qi]; o1 += so1[qi];
    const float inv = 1.0f / l;
    ((float2*)o_ws)[(size_t)fh * NBATCH + b] = make_float2(o0 * inv, o1 * inv);
  }
}

// ---------------- K3: fold out_proj into lin (per-block, LDS), logits + softmax ----
// Wcomb[t][f*8+e'] = sum_i lin_w[t][f*8+i] * out_proj_w[i][e']
// bcomb[t] = lin_b[t] + sum_{f,i} lin_w[t][f*8+i] * out_proj_b[i]
__global__ __launch_bounds__(256) void k3_final(
    const float* __restrict__ o_ws, const float* __restrict__ opw,
    const float* __restrict__ opb,  const float* __restrict__ lw,
    const float* __restrict__ lb,   float* __restrict__ out)
{
  __shared__ float sWc[4096];   // [t][256]
  __shared__ float sbc[16];
  __shared__ float sWo[64];
  const int tid = threadIdx.x;
  if (tid < 64) sWo[tid] = opw[tid];
  __syncthreads();
  #pragma unroll
  for (int i = tid; i < 4096; i += 256) {
    const int t = i >> 8, fe = i & 255;
    const int f8 = fe & ~7, e2 = fe & 7;
    float acc = 0.0f;
    #pragma unroll
    for (int e = 0; e < 8; ++e) acc = fmaf(lw[t*256 + f8 + e], sWo[e*8 + e2], acc);
    sWc[i] = acc;
  }
  {  // bcomb: 16 lanes per t, shuffle-reduce within 16-lane groups
    const int t = tid >> 4, seg = tid & 15;
    float acc = 0.0f;
    #pragma unroll
    for (int j = 0; j < 16; ++j) {
      const int fe = seg * 16 + j;
      acc = fmaf(lw[t*256 + fe], opb[fe & 7], acc);
    }
    #pragma unroll
    for (int off = 8; off >= 1; off >>= 1) acc += __shfl_xor(acc, off, 64);
    if (seg == 0) sbc[t] = acc + lb[t];
  }
  __syncthreads();

  const int gid = blockIdx.x * 256 + tid;  // 16384 threads
  const int b = gid >> 4;
  const int t = gid & 15;
  const float2* op = (const float2*)o_ws;
  const float2* wp = (const float2*)sWc + t * 128;
  float acc = sbc[t];
  #pragma unroll 8
  for (int fh = 0; fh < NFH; ++fh) {
    const float2 ov = op[(size_t)fh * NBATCH + b];
    const float2 wv = wp[fh];
    acc = fmaf(ov.x, wv.x, fmaf(ov.y, wv.y, acc));
  }
  // softmax across the 16 lanes sharing b (lanes are 16-aligned groups in a wave)
  float mx = acc;
  #pragma unroll
  for (int off = 8; off >= 1; off >>= 1) mx = fmaxf(mx, __shfl_xor(mx, off, 64));
  const float p = expf(acc - mx);
  float s = p;
  #pragma unroll
  for (int off = 8; off >= 1; off >>= 1) s += __shfl_xor(s, off, 64);
  out[gid] = p / s;
}

extern "C" void kernel_launch(void* const* d_in, const int* in_sizes, int n_in,
                              void* d_out, int out_size, void* d_ws, size_t ws_size,
                              hipStream_t stream)
{
  const float* x   = (const float*)d_in[0];
  const float* emb = (const float*)d_in[1];
  const float* ipw = (const float*)d_in[2];
  const float* ipb = (const float*)d_in[3];
  const float* opw = (const float*)d_in[4];
  const float* opb = (const float*)d_in[5];
  const float* lw  = (const float*)d_in[6];
  const float* lb  = (const float*)d_in[7];

  float* ws    = (float*)d_ws;
  float* q_ws  = ws;             // 128*1024*2 = 262144 floats
  float* kv_ws = ws + 262144;    // 128*1024*4 = 524288 floats
  float* o_ws  = ws + 786432;    // 128*1024*2 = 262144 floats

  k1_embed_qkv<<<dim3(4, NF), 256, 0, stream>>>(x, emb, ipw, ipb, q_ws, kv_ws);
  k2_attn<<<dim3(4, NFH), 512, 0, stream>>>(q_ws, kv_ws, o_ws);
  k3_final<<<64, 256, 0, stream>>>(o_ws, opw, opb, lw, lb, (float*)d_out);
}

// Round 4
// 109.186 us; speedup vs baseline: 1.1456x; 1.0048x over previous
//
#include <hip/hip_runtime.h>
#include <math.h>

#define NF 32
#define NB 1100
#define NE 8
#define NH 4
#define NBATCH 1024
#define NFH 128  // NF*NH

typedef float vf2 __attribute__((ext_vector_type(2)));

__device__ __forceinline__ float fexp2(float x){
#if __has_builtin(__builtin_amdgcn_exp2f)
  return __builtin_amdgcn_exp2f(x);
#else
  return exp2f(x);
#endif
}

// bins[i] exactly as np.linspace(-1, 300, 1100) in float64:
// step = 301/1099 (f64), bins[i] = fl(fl(i*step) + (-1)), bins[1099] = 300.0 forced.
__device__ __forceinline__ double bin_at(int i){
  #pragma clang fp contract(off)
  const double step = 301.0 / 1099.0;
  if (i == NB - 1) return 300.0;
  return (double)i * step + (-1.0);
}

// ---------------- K1: bin search + embedding gather + QKV projection ----------------
__global__ __launch_bounds__(128) void k1_embed_qkv(
    const float* __restrict__ x, const float* __restrict__ emb,
    const float* __restrict__ W, const float* __restrict__ bias,
    float* __restrict__ q_ws, float* __restrict__ kv_ws)
{
  __shared__ float sW[192];
  __shared__ float sB[24];
  const int tid = threadIdx.x;
  for (int i = tid; i < 192; i += 128) sW[i] = W[i];
  if (tid < 24)  sB[tid] = bias[tid];
  __syncthreads();

  const int f = blockIdx.y;
  const int b = blockIdx.x * 128 + tid;

  float xv = x[b * NF + f];
  xv = fminf(fmaxf(xv, -1.0f), 300.0f);
  const double xd = (double)xv;

  // searchsorted side='left': first i with bins[i] >= xd
  int lo = 0, hi = NB;
  while (lo < hi) {
    const int mid = (lo + hi) >> 1;
    if (bin_at(mid) < xd) lo = mid + 1; else hi = mid;
  }
  const int idx = lo;  // in [0, 1099] since xd <= 300 = bins[1099]

  const float4* ep = (const float4*)(emb + ((size_t)f * NB + idx) * NE);
  const float4 e0 = ep[0], e1 = ep[1];
  const float xe[8] = {e0.x, e0.y, e0.z, e0.w, e1.x, e1.y, e1.z, e1.w};

  float qv[8], kv[8], vv[8];
  #pragma unroll
  for (int i = 0; i < 8; ++i) { qv[i] = sB[i]; kv[i] = sB[8+i]; vv[i] = sB[16+i]; }
  #pragma unroll
  for (int j = 0; j < 8; ++j) {
    const float xj = xe[j];
    #pragma unroll
    for (int i = 0; i < 8; ++i) {
      qv[i] = fmaf(xj, sW[      i*8 + j], qv[i]);
      kv[i] = fmaf(xj, sW[ 64 + i*8 + j], kv[i]);
      vv[i] = fmaf(xj, sW[128 + i*8 + j], vv[i]);
    }
  }

  // q pre-scaled by log2(e)/sqrt(hd) so K2 can use exp2 directly
  const float QS = (float)(1.4426950408889634 / 1.4142135623730951);
  float2* qp = (float2*)q_ws;
  float4* kvp = (float4*)kv_ws;
  #pragma unroll
  for (int h = 0; h < NH; ++h) {
    const int fh = f * NH + h;
    qp [fh * NBATCH + b] = make_float2(qv[2*h] * QS, qv[2*h+1] * QS);
    kvp[fh * NBATCH + b] = make_float4(kv[2*h], kv[2*h+1], vv[2*h], vv[2*h+1]);
  }
}

// ---------------- K2: batch-attention per (f,h), single-pass softmax ----------------
// 512 threads: 256 q-rows x 2 c-halves, 2-c-per-iter inner loop via float2 vectors
// (plain C arithmetic — compiler emits v_pk_fma_f32 or scalar FMA, both correct).
// LDS layout: skk[t] = {k0[2t],k0[2t+1],k1[2t],k1[2t+1]}, svv likewise for v.
__global__ __launch_bounds__(512) void k2_attn(
    const float* __restrict__ q_ws, const float* __restrict__ kv_ws,
    float* __restrict__ o_ws)
{
  __shared__ float4 skk[512];      // 8 KB
  __shared__ float4 svv[512];      // 8 KB
  __shared__ float sred[8];
  __shared__ float sl[256], so0[256], so1[256];
  const int tid = threadIdx.x;     // 0..511
  const int fh = blockIdx.y;

  // stage K/V (pair-interleaved) and find max ||k||^2 (Cauchy-Schwarz bound)
  const float4* kvg = (const float4*)kv_ws + (size_t)fh * NBATCH;
  const float4 a0 = kvg[2*tid], a1 = kvg[2*tid+1];
  skk[tid] = make_float4(a0.x, a1.x, a0.y, a1.y);
  svv[tid] = make_float4(a0.z, a1.z, a0.w, a1.w);
  float mx2 = fmaxf(fmaf(a0.x, a0.x, a0.y * a0.y), fmaf(a1.x, a1.x, a1.y * a1.y));
  #pragma unroll
  for (int off = 32; off >= 1; off >>= 1)
    mx2 = fmaxf(mx2, __shfl_xor(mx2, off, 64));
  if ((tid & 63) == 0) sred[tid >> 6] = mx2;
  __syncthreads();
  float Mn2 = sred[0];
  #pragma unroll
  for (int w = 1; w < 8; ++w) Mn2 = fmaxf(Mn2, sred[w]);
  const float Mn = sqrtf(Mn2);

  const int qi = tid & 255;
  const int half = tid >> 8;
  const int b = blockIdx.x * 256 + qi;   // one query row per thread pair
  const float2 q = ((const float2*)q_ws)[(size_t)fh * NBATCH + b];
  const float negm = -sqrtf(fmaf(q.x, q.x, q.y * q.y)) * Mn;  // -(bound >= all scores)

  const vf2 qxx = {q.x, q.x};
  const vf2 qyy = {q.y, q.y};
  const vf2 nm2 = {negm, negm};
  vf2 lp = {0.0f, 0.0f}, o0p = {0.0f, 0.0f}, o1p = {0.0f, 0.0f};

  const int p0 = half << 8;              // pair-index start: 256 pairs per half
  #pragma unroll 8
  for (int i = 0; i < 256; ++i) {
    const float4 kk = skk[p0 + i];       // uniform-address LDS broadcast
    const float4 vv = svv[p0 + i];
    const vf2 k0p = {kk.x, kk.y}, k1p = {kk.z, kk.w};
    const vf2 v0p = {vv.x, vv.y}, v1p = {vv.z, vv.w};
    const vf2 s = qxx * k0p + qyy * k1p + nm2;   // scaled scores - m (<= 0 + 1ulp)
    vf2 pp; pp.x = fexp2(s.x); pp.y = fexp2(s.y);
    lp  += pp;
    o0p += pp * v0p;
    o1p += pp * v1p;
  }
  float l = lp.x + lp.y, o0 = o0p.x + o0p.y, o1 = o1p.x + o1p.y;

  if (half == 1) { sl[qi] = l; so0[qi] = o0; so1[qi] = o1; }
  __syncthreads();
  if (half == 0) {
    l += sl[qi]; o0 += so0[qi]; o1 += so1[qi];
    const float inv = 1.0f / l;
    ((float2*)o_ws)[(size_t)fh * NBATCH + b] = make_float2(o0 * inv, o1 * inv);
  }
}

// ---------------- K3: fold out_proj into lin (per-block, LDS), logits + softmax ----
__global__ __launch_bounds__(256) void k3_final(
    const float* __restrict__ o_ws, const float* __restrict__ opw,
    const float* __restrict__ opb,  const float* __restrict__ lw,
    const float* __restrict__ lb,   float* __restrict__ out)
{
  __shared__ float sWc[4096];   // [t][256]
  __shared__ float sbc[16];
  __shared__ float sWo[64];
  const int tid = threadIdx.x;
  if (tid < 64) sWo[tid] = opw[tid];
  __syncthreads();
  #pragma unroll
  for (int i = tid; i < 4096; i += 256) {
    const int t = i >> 8, fe = i & 255;
    const int f8 = fe & ~7, e2 = fe & 7;
    float acc = 0.0f;
    #pragma unroll
    for (int e = 0; e < 8; ++e) acc = fmaf(lw[t*256 + f8 + e], sWo[e*8 + e2], acc);
    sWc[i] = acc;
  }
  {  // bcomb: 16 lanes per t, shuffle-reduce within 16-lane groups
    const int t = tid >> 4, seg = tid & 15;
    float acc = 0.0f;
    #pragma unroll
    for (int j = 0; j < 16; ++j) {
      const int fe = seg * 16 + j;
      acc = fmaf(lw[t*256 + fe], opb[fe & 7], acc);
    }
    #pragma unroll
    for (int off = 8; off >= 1; off >>= 1) acc += __shfl_xor(acc, off, 64);
    if (seg == 0) sbc[t] = acc + lb[t];
  }
  __syncthreads();

  const int gid = blockIdx.x * 256 + tid;  // 16384 threads
  const int b = gid >> 4;
  const int t = gid & 15;
  const float2* op = (const float2*)o_ws;
  const float2* wp = (const float2*)sWc + t * 128;
  float acc = sbc[t];
  #pragma unroll 8
  for (int fh = 0; fh < NFH; ++fh) {
    const float2 ov = op[(size_t)fh * NBATCH + b];
    const float2 wv = wp[fh];
    acc = fmaf(ov.x, wv.x, fmaf(ov.y, wv.y, acc));
  }
  // softmax across the 16 lanes sharing b
  float mx = acc;
  #pragma unroll
  for (int off = 8; off >= 1; off >>= 1) mx = fmaxf(mx, __shfl_xor(mx, off, 64));
  const float p = expf(acc - mx);
  float s = p;
  #pragma unroll
  for (int off = 8; off >= 1; off >>= 1) s += __shfl_xor(s, off, 64);
  out[gid] = p / s;
}

extern "C" void kernel_launch(void* const* d_in, const int* in_sizes, int n_in,
                              void* d_out, int out_size, void* d_ws, size_t ws_size,
                              hipStream_t stream)
{
  const float* x   = (const float*)d_in[0];
  const float* emb = (const float*)d_in[1];
  const float* ipw = (const float*)d_in[2];
  const float* ipb = (const float*)d_in[3];
  const float* opw = (const float*)d_in[4];
  const float* opb = (const float*)d_in[5];
  const float* lw  = (const float*)d_in[6];
  const float* lb  = (const float*)d_in[7];

  float* ws    = (float*)d_ws;
  float* q_ws  = ws;             // 128*1024*2 = 262144 floats
  float* kv_ws = ws + 262144;    // 128*1024*4 = 524288 floats
  float* o_ws  = ws + 786432;    // 128*1024*2 = 262144 floats

  k1_embed_qkv<<<dim3(8, NF), 128, 0, stream>>>(x, emb, ipw, ipb, q_ws, kv_ws);
  k2_attn<<<dim3(4, NFH), 512, 0, stream>>>(q_ws, kv_ws, o_ws);
  k3_final<<<64, 256, 0, stream>>>(o_ws, opw, opb, lw, lb, (float*)d_out);
}

// Round 6
// 108.211 us; speedup vs baseline: 1.1560x; 1.0090x over previous
//
#include <hip/hip_runtime.h>
#include <math.h>

#define NF 32
#define NB 1100
#define NE 8
#define NH 4
#define NBATCH 1024
#define NFH 128  // NF*NH

typedef float vf2 __attribute__((ext_vector_type(2)));

__device__ __forceinline__ float fexp2(float x){
#if __has_builtin(__builtin_amdgcn_exp2f)
  return __builtin_amdgcn_exp2f(x);
#else
  return exp2f(x);
#endif
}

// bins[i] exactly as np.linspace(-1, 300, 1100) in float64:
// step = 301/1099 (f64), bins[i] = fl(fl(i*step) + (-1)), bins[1099] = 300.0 forced.
__device__ __forceinline__ double bin_at(int i){
  #pragma clang fp contract(off)
  const double step = 301.0 / 1099.0;
  if (i == NB - 1) return 300.0;
  return (double)i * step + (-1.0);
}

// ---------------- K12: fused embed+QKV (per-head) + batch-attention ----------------
// Grid (4 bq, 128 fh), 512 threads. Each block re-derives K/V for all 1024 rows of
// its (f,h) (2 rows/thread) and q for its 256 rows; then the single-pass
// Cauchy-Schwarz-bounded softmax attention (2 c-halves per q-row, LDS merge).
// 16 designated blocks also emit one row each of Wcomb/bcomb for K3.
__global__ __launch_bounds__(512) void k12_attn(
    const float* __restrict__ x,   const float* __restrict__ emb,
    const float* __restrict__ W,   const float* __restrict__ bias,
    const float* __restrict__ opw, const float* __restrict__ opb,
    const float* __restrict__ lw,  const float* __restrict__ lb,
    float* __restrict__ o_ws, float* __restrict__ Wcomb, float* __restrict__ bcomb)
{
  __shared__ float skkf[2048];     // pair-interleaved: [4i+par]=k0(row 2i+par), [4i+2+par]=k1
  __shared__ float svvf[2048];
  __shared__ float sq[512];        // q (scaled) for this block's 256 rows
  __shared__ float sred[8];
  __shared__ float sl[256], so0[256], so1[256];
  __shared__ float sWb[48];        // rows {q0,q1,k0,k1,v0,v1} x 8 cols for this head
  __shared__ float sBb[6];

  const int tid = threadIdx.x;     // 0..511
  const int bq  = blockIdx.x;      // 0..3
  const int fh  = blockIdx.y;      // 0..127
  const int f   = fh >> 2, h = fh & 3;

  if (tid < 48) {
    const int r = tid >> 3, j = tid & 7;   // r: 0,1=q 2,3=k 4,5=v
    sWb[tid] = W[((r >> 1) * 8 + 2 * h + (r & 1)) * 8 + j];
  }
  if (tid < 6) sBb[tid] = bias[(tid >> 1) * 8 + 2 * h + (tid & 1)];
  __syncthreads();

  const float QS = (float)(1.4426950408889634 / 1.4142135623730951);
  const int qlo = bq << 8;
  float mx2 = 0.0f;

  #pragma unroll
  for (int r2 = 0; r2 < 2; ++r2) {
    const int row = tid + (r2 << 9);
    float xv = x[row * NF + f];
    xv = fminf(fmaxf(xv, -1.0f), 300.0f);
    const double xd = (double)xv;
    // searchsorted side='left': first i with bins[i] >= xd
    int lo = 0, hi = NB;
    while (lo < hi) {
      const int mid = (lo + hi) >> 1;
      if (bin_at(mid) < xd) lo = mid + 1; else hi = mid;
    }
    const float4* ep = (const float4*)(emb + ((size_t)f * NB + lo) * NE);
    const float4 e0 = ep[0], e1 = ep[1];
    const float xe[8] = {e0.x, e0.y, e0.z, e0.w, e1.x, e1.y, e1.z, e1.w};

    float k0 = sBb[2], k1 = sBb[3], v0 = sBb[4], v1 = sBb[5];
    #pragma unroll
    for (int j = 0; j < 8; ++j) {
      k0 = fmaf(xe[j], sWb[16 + j], k0);
      k1 = fmaf(xe[j], sWb[24 + j], k1);
      v0 = fmaf(xe[j], sWb[32 + j], v0);
      v1 = fmaf(xe[j], sWb[40 + j], v1);
    }
    const int i = row >> 1, par = row & 1;
    skkf[4*i + par]     = k0;  skkf[4*i + 2 + par] = k1;
    svvf[4*i + par]     = v0;  svvf[4*i + 2 + par] = v1;
    mx2 = fmaxf(mx2, fmaf(k0, k0, k1 * k1));

    const unsigned qi = (unsigned)(row - qlo);
    if (qi < 256u) {
      float q0 = sBb[0], q1 = sBb[1];
      #pragma unroll
      for (int j = 0; j < 8; ++j) {
        q0 = fmaf(xe[j], sWb[j],     q0);
        q1 = fmaf(xe[j], sWb[8 + j], q1);
      }
      sq[2*qi] = q0 * QS;  sq[2*qi + 1] = q1 * QS;
    }
  }
  #pragma unroll
  for (int off = 32; off >= 1; off >>= 1)
    mx2 = fmaxf(mx2, __shfl_xor(mx2, off, 64));
  if ((tid & 63) == 0) sred[tid >> 6] = mx2;
  __syncthreads();

  float Mn2 = sred[0];
  #pragma unroll
  for (int w = 1; w < 8; ++w) Mn2 = fmaxf(Mn2, sred[w]);
  const float Mn = sqrtf(Mn2);

  const int qi = tid & 255;
  const int half = tid >> 8;
  const float2 q = ((const float2*)sq)[qi];
  const float negm = -sqrtf(fmaf(q.x, q.x, q.y * q.y)) * Mn;  // -(bound >= all scores)

  const vf2 qxx = {q.x, q.x};
  const vf2 qyy = {q.y, q.y};
  const vf2 nm2 = {negm, negm};
  vf2 lp = {0.0f, 0.0f}, o0p = {0.0f, 0.0f}, o1p = {0.0f, 0.0f};

  const float4* skk = (const float4*)skkf;
  const float4* svv = (const float4*)svvf;
  const int p0 = half << 8;              // 256 pairs per half
  #pragma unroll 8
  for (int i = 0; i < 256; ++i) {
    const float4 kk = skk[p0 + i];       // uniform-address LDS broadcast
    const float4 vv = svv[p0 + i];
    const vf2 k0p = {kk.x, kk.y}, k1p = {kk.z, kk.w};
    const vf2 v0p = {vv.x, vv.y}, v1p = {vv.z, vv.w};
    const vf2 s = qxx * k0p + qyy * k1p + nm2;   // scaled scores - m (<= 0 + 1ulp)
    vf2 pp; pp.x = fexp2(s.x); pp.y = fexp2(s.y);
    lp  += pp;
    o0p += pp * v0p;
    o1p += pp * v1p;
  }
  float l = lp.x + lp.y, o0 = o0p.x + o0p.y, o1 = o1p.x + o1p.y;

  if (half == 1) { sl[qi] = l; so0[qi] = o0; so1[qi] = o1; }
  __syncthreads();
  if (half == 0) {
    l += sl[qi]; o0 += so0[qi]; o1 += so1[qi];
    const float inv = 1.0f / l;
    const int b = qlo + qi;
    ((float2*)o_ws)[(size_t)fh * NBATCH + b] = make_float2(o0 * inv, o1 * inv);
  }

  // ---- 16 designated blocks emit Wcomb row t=fh and bcomb[t] ----
  if (bq == 0 && fh < 16) {
    const int t = fh;
    float bacc = 0.0f;
    if (tid < 256) {
      const int f8 = tid & ~7, e2 = tid & 7;
      float wacc = 0.0f;
      #pragma unroll
      for (int e = 0; e < 8; ++e)
        wacc = fmaf(lw[t*256 + f8 + e], opw[e*8 + e2], wacc);
      Wcomb[t*256 + tid] = wacc;
      bacc = lw[t*256 + tid] * opb[tid & 7];
    }
    #pragma unroll
    for (int off = 32; off >= 1; off >>= 1) bacc += __shfl_xor(bacc, off, 64);
    if ((tid & 63) == 0) sred[tid >> 6] = bacc;   // safe: all pre-loop reads done
    __syncthreads();
    if (tid == 0) bcomb[t] = sred[0] + sred[1] + sred[2] + sred[3] + lb[t];
  }
}

// ---------------- K3: logits = o . Wcomb^T + bcomb, softmax over 16 ----------------
// 256 blocks x 64 threads (one per (b,t) pair) for full-CU spread.
__global__ __launch_bounds__(64) void k3_final(
    const float* __restrict__ o_ws, const float* __restrict__ Wcomb,
    const float* __restrict__ bcomb, float* __restrict__ out)
{
  __shared__ float sWc[4096];   // [t][256]
  __shared__ float sbc[16];
  const int tid = threadIdx.x;
  const float4* wg = (const float4*)Wcomb;
  float4* ws4 = (float4*)sWc;
  #pragma unroll
  for (int i = tid; i < 1024; i += 64) ws4[i] = wg[i];
  if (tid < 16) sbc[tid] = bcomb[tid];
  __syncthreads();

  const int gid = blockIdx.x * 64 + tid;  // 16384 threads
  const int b = gid >> 4;
  const int t = gid & 15;
  const float2* op = (const float2*)o_ws;
  const float2* wp = (const float2*)sWc + t * 128;
  float acc = sbc[t];
  #pragma unroll 8
  for (int fh = 0; fh < NFH; ++fh) {
    const float2 ov = op[(size_t)fh * NBATCH + b];
    const float2 wv = wp[fh];
    acc = fmaf(ov.x, wv.x, fmaf(ov.y, wv.y, acc));
  }
  // softmax across the 16 lanes sharing b
  float mx = acc;
  #pragma unroll
  for (int off = 8; off >= 1; off >>= 1) mx = fmaxf(mx, __shfl_xor(mx, off, 64));
  const float p = expf(acc - mx);
  float s = p;
  #pragma unroll
  for (int off = 8; off >= 1; off >>= 1) s += __shfl_xor(s, off, 64);
  out[gid] = p / s;
}

extern "C" void kernel_launch(void* const* d_in, const int* in_sizes, int n_in,
                              void* d_out, int out_size, void* d_ws, size_t ws_size,
                              hipStream_t stream)
{
  const float* x   = (const float*)d_in[0];
  const float* emb = (const float*)d_in[1];
  const float* ipw = (const float*)d_in[2];
  const float* ipb = (const float*)d_in[3];
  const float* opw = (const float*)d_in[4];
  const float* opb = (const float*)d_in[5];
  const float* lw  = (const float*)d_in[6];
  const float* lb  = (const float*)d_in[7];

  float* ws    = (float*)d_ws;
  float* o_ws  = ws;             // 128*1024*2 = 262144 floats (1 MB)
  float* Wcomb = ws + 262144;    // 4096 floats
  float* bcomb = ws + 266240;    // 16 floats

  k12_attn<<<dim3(4, NFH), 512, 0, stream>>>(x, emb, ipw, ipb, opw, opb, lw, lb,
                                             o_ws, Wcomb, bcomb);
  k3_final<<<256, 64, 0, stream>>>(o_ws, Wcomb, bcomb, (float*)d_out);
}